// Round 1
// baseline (35.106 us; speedup 1.0000x reference)
//
#include <hip/hip_runtime.h>

// Problem geometry (fixed by reference setup_inputs)
#define B  4
#define D  48
#define H  128
#define W  240
#define H4 512   // 4*H
#define W4 960   // 4*W

// Kernel 1: per coarse pixel, top-2 over disparity + softmax + soft-argmax.
// cost layout: [B,1,D,H,W]; disp4 layout: [B,H,W]
__global__ void __launch_bounds__(256)
topk_softargmax_kernel(const float* __restrict__ cost, float* __restrict__ disp4) {
    int idx = blockIdx.x * blockDim.x + threadIdx.x;
    const int npix = B * H * W;
    if (idx >= npix) return;
    int b   = idx / (H * W);
    int rem = idx - b * (H * W);               // y*W + x
    const float* p = cost + (size_t)b * D * H * W + rem;

    float v1 = -INFINITY, v2 = -INFINITY;
    int   i1 = 0,          i2 = 0;
    #pragma unroll 4
    for (int d = 0; d < D; ++d) {
        float v = p[(size_t)d * (H * W)];
        if (v > v1)      { v2 = v1; i2 = i1; v1 = v; i1 = d; }
        else if (v > v2) { v2 = v;  i2 = d; }
    }
    // softmax over [v1, v2] (v1 >= v2), then weighted index sum
    float e     = expf(v2 - v1);
    float inv   = 1.0f / (1.0f + e);
    disp4[idx]  = ((float)i1 + (float)i2 * e) * inv;
}

// Kernel 2: 3x3 unfold (zero pad) + nearest 4x upsample + weighted sum by spg, *4.
// One thread -> 4 consecutive output pixels (same coarse source pixel).
// spg layout: [B,9,H4,W4]; out layout: [B,H4,W4]
__global__ void __launch_bounds__(256)
upfeat_kernel(const float* __restrict__ disp4, const float* __restrict__ spg,
              float* __restrict__ out) {
    int t = blockIdx.x * blockDim.x + threadIdx.x;
    const int nt = B * H4 * W;   // W = W4/4 thread-groups per row
    if (t >= nt) return;

    int xs  = t % W;
    int tmp = t / W;
    int Y   = tmp % H4;
    int b   = tmp / H4;
    int y   = Y >> 2;

    // 3x3 disp neighborhood (zero outside)
    float dv[9];
    const float* dp = disp4 + (size_t)b * (H * W);
    #pragma unroll
    for (int dy = 0; dy < 3; ++dy) {
        int yy = y + dy - 1;
        #pragma unroll
        for (int dx = 0; dx < 3; ++dx) {
            int xx = xs + dx - 1;
            dv[dy * 3 + dx] = (yy >= 0 && yy < H && xx >= 0 && xx < W)
                              ? dp[yy * W + xx] : 0.0f;
        }
    }

    const float* sp = spg + (((size_t)b * 9) * H4 + Y) * W4 + 4 * xs;
    float4 acc = make_float4(0.f, 0.f, 0.f, 0.f);
    #pragma unroll
    for (int k = 0; k < 9; ++k) {
        float4 s = *reinterpret_cast<const float4*>(sp + (size_t)k * (H4 * W4));
        float  d = dv[k];
        acc.x += d * s.x; acc.y += d * s.y; acc.z += d * s.z; acc.w += d * s.w;
    }
    acc.x *= 4.f; acc.y *= 4.f; acc.z *= 4.f; acc.w *= 4.f;

    *reinterpret_cast<float4*>(out + ((size_t)b * H4 + Y) * W4 + 4 * xs) = acc;
}

extern "C" void kernel_launch(void* const* d_in, const int* in_sizes, int n_in,
                              void* d_out, int out_size, void* d_ws, size_t ws_size,
                              hipStream_t stream) {
    const float* cost = (const float*)d_in[0];   // [B,1,D,H,W]
    const float* spg  = (const float*)d_in[1];   // [B,9,H4,W4]
    float* outp  = (float*)d_out;                // [B,H4,W4]
    float* disp4 = (float*)d_ws;                 // [B,H,W] scratch (491 KB)

    {
        const int n = B * H * W;
        topk_softargmax_kernel<<<(n + 255) / 256, 256, 0, stream>>>(cost, disp4);
    }
    {
        const int n = B * H4 * W;
        upfeat_kernel<<<(n + 255) / 256, 256, 0, stream>>>(disp4, spg, outp);
    }
}

// Round 2
// 24.765 us; speedup vs baseline: 1.4176x; 1.4176x over previous
//
#include <hip/hip_runtime.h>

// Problem geometry (fixed by reference setup_inputs)
#define B  4
#define D  48
#define H  128
#define W  240
#define H4 512   // 4*H
#define W4 960   // 4*W

// Kernel 1: per coarse pixel, top-2 over disparity + softmax + soft-argmax.
// cost layout: [B,1,D,H,W]; disp4 layout: [B,H,W]
// Full unroll: issue all 48 strided loads up front (latency hiding via ILP),
// then run the sequential top-2 scan on registers.
__global__ void __launch_bounds__(256)
topk_softargmax_kernel(const float* __restrict__ cost, float* __restrict__ disp4) {
    int idx = blockIdx.x * blockDim.x + threadIdx.x;
    const int npix = B * H * W;
    if (idx >= npix) return;
    int b   = idx / (H * W);
    int rem = idx - b * (H * W);               // y*W + x
    const float* p = cost + (size_t)b * D * H * W + rem;

    float v[D];
    #pragma unroll
    for (int d = 0; d < D; ++d) v[d] = p[(size_t)d * (H * W)];

    float v1 = -INFINITY, v2 = -INFINITY;
    int   i1 = 0,          i2 = 0;
    #pragma unroll
    for (int d = 0; d < D; ++d) {
        float x = v[d];
        if (x > v1)      { v2 = v1; i2 = i1; v1 = x; i1 = d; }
        else if (x > v2) { v2 = x;  i2 = d; }
    }
    // softmax over [v1, v2] (v1 >= v2), then weighted index sum
    float e     = expf(v2 - v1);
    float inv   = 1.0f / (1.0f + e);
    disp4[idx]  = ((float)i1 + (float)i2 * e) * inv;
}

// Kernel 2: 3x3 unfold (zero pad) + nearest 4x upsample + weighted sum by spg, *4.
// One thread -> 4 consecutive output pixels (same coarse source pixel).
// spg layout: [B,9,H4,W4]; out layout: [B,H4,W4]
__global__ void __launch_bounds__(256)
upfeat_kernel(const float* __restrict__ disp4, const float* __restrict__ spg,
              float* __restrict__ out) {
    int t = blockIdx.x * blockDim.x + threadIdx.x;
    const int nt = B * H4 * W;   // W = W4/4 thread-groups per row
    if (t >= nt) return;

    int xs  = t % W;
    int tmp = t / W;
    int Y   = tmp % H4;
    int b   = tmp / H4;
    int y   = Y >> 2;

    // 3x3 disp neighborhood (zero outside)
    float dv[9];
    const float* dp = disp4 + (size_t)b * (H * W);
    #pragma unroll
    for (int dy = 0; dy < 3; ++dy) {
        int yy = y + dy - 1;
        #pragma unroll
        for (int dx = 0; dx < 3; ++dx) {
            int xx = xs + dx - 1;
            dv[dy * 3 + dx] = (yy >= 0 && yy < H && xx >= 0 && xx < W)
                              ? dp[yy * W + xx] : 0.0f;
        }
    }

    const float* sp = spg + (((size_t)b * 9) * H4 + Y) * W4 + 4 * xs;
    float4 acc = make_float4(0.f, 0.f, 0.f, 0.f);
    #pragma unroll
    for (int k = 0; k < 9; ++k) {
        float4 s = *reinterpret_cast<const float4*>(sp + (size_t)k * (H4 * W4));
        float  d = dv[k];
        acc.x += d * s.x; acc.y += d * s.y; acc.z += d * s.z; acc.w += d * s.w;
    }
    acc.x *= 4.f; acc.y *= 4.f; acc.z *= 4.f; acc.w *= 4.f;

    *reinterpret_cast<float4*>(out + ((size_t)b * H4 + Y) * W4 + 4 * xs) = acc;
}

extern "C" void kernel_launch(void* const* d_in, const int* in_sizes, int n_in,
                              void* d_out, int out_size, void* d_ws, size_t ws_size,
                              hipStream_t stream) {
    const float* cost = (const float*)d_in[0];   // [B,1,D,H,W]
    const float* spg  = (const float*)d_in[1];   // [B,9,H4,W4]
    float* outp  = (float*)d_out;                // [B,H4,W4]
    float* disp4 = (float*)d_ws;                 // [B,H,W] scratch (491 KB)

    {
        const int n = B * H * W;
        topk_softargmax_kernel<<<(n + 255) / 256, 256, 0, stream>>>(cost, disp4);
    }
    {
        const int n = B * H4 * W;
        upfeat_kernel<<<(n + 255) / 256, 256, 0, stream>>>(disp4, spg, outp);
    }
}